// Round 4
// baseline (264.939 us; speedup 1.0000x reference)
//
#include <hip/hip_runtime.h>
#include <math.h>

#define H  128
#define S  8
#define BB 8   // batches per block, one wave each (512-thread blocks)

__device__ __forceinline__ float wave_sum(float v) {
    #pragma unroll
    for (int off = 32; off; off >>= 1) v += __shfl_xor(v, off, 64);
    return v;
}

// Single fused kernel, half-wave slot layout (see R3). R4: __expf/v_rcp fast
// math in softmax (arg range [-m,0], error << 7.4e-4 threshold) + float4 LDS
// reads of wm in the epilogue.
__global__ __launch_bounds__(512) void fused_kernel(
        const float* __restrict__ memory,    // [R,S,H]
        const float* __restrict__ o_emb_w,   // [H]
        const float* __restrict__ o_emb_r,   // [B,H]
        const float* __restrict__ attn_W,    // [H,H]
        const float* __restrict__ sim_w,     // [2H]
        const float* __restrict__ sim_b,     // [1]
        const float* __restrict__ forget_w,  // [2H]
        const int*   __restrict__ o_rg_p,
        const int*   __restrict__ d_rg,      // [B]
        float* __restrict__ out) {           // [B,H]
    __shared__ float v1s[H], v2s[H];
    __shared__ float wm_lds[BB][H];

    const int u  = threadIdx.x;
    const int wv = u >> 6;     // wave id == batch-within-block (0..7)
    const int L  = u & 63;
    const int c  = L & 31;     // float4 column index
    const int hi = L >> 5;     // 0 = even slots, 1 = odd slots
    const int b  = blockIdx.x * BB + wv;

    const int o_rg = o_rg_p[0];
    const int r    = d_rg[b];

    // ---- gather first (latency-heavy): 4 x 16B loads = whole 4 KB region ----
    const float4* src4 = (const float4*)(memory + (size_t)r * (S * H));
    float4 rows[4];
    #pragma unroll
    for (int j = 0; j < 4; ++j) rows[j] = src4[j * 64 + L];
    const float2 oe = ((const float2*)o_emb_r)[(size_t)b * (H / 2) + L];

    // ---- v1 = attn_W @ sim_w[:H], v2 = attn_W @ sim_w[H:], threads 0..255 ----
    if (u < 256) {
        const int row = u & 127;
        const float4* wr = (const float4*)(attn_W + row * H);
        const float4* sv = (const float4*)(sim_w + (u >> 7) * H);
        float a = 0.f;
        #pragma unroll 8
        for (int j = 0; j < 32; ++j) {
            float4 w = wr[j], x = sv[j];
            a += w.x * x.x + w.y * x.y + w.z * x.z + w.w * x.w;
        }
        if (u < 128) v1s[row] = a; else v2s[row] = a;
    }
    __syncthreads();

    // ---- rare: this wave's region is the written one -> forget-gate fix ----
    if (r == o_rg) {
        const float4 ow4 = ((const float4*)o_emb_w)[c];
        const float4 f24 = ((const float4*)(forget_w + H))[c];
        const float2 ow2 = ((const float2*)o_emb_w)[L];
        const float2 f12 = ((const float2*)forget_w)[L];
        const float base = wave_sum(ow2.x * f12.x + ow2.y * f12.y);
        #pragma unroll
        for (int j = 0; j < 4; ++j) {
            float v = rows[j].x * f24.x + rows[j].y * f24.y
                    + rows[j].z * f24.z + rows[j].w * f24.w;
            #pragma unroll
            for (int off = 1; off <= 16; off <<= 1) v += __shfl_xor(v, off, 64);
            float g = 1.f / (1.f + __expf(-(base + v)));
            rows[j].x = rows[j].x * (1.f - g) + ow4.x * g;
            rows[j].y = rows[j].y * (1.f - g) + ow4.y * g;
            rows[j].z = rows[j].z * (1.f - g) + ow4.z * g;
            rows[j].w = rows[j].w * (1.f - g) + ow4.w * g;
        }
    }

    // ---- attention logits ----
    const float2 vv1 = ((const float2*)v1s)[L];
    const float  qs  = wave_sum(oe.x * vv1.x + oe.y * vv1.y);
    const float4 vv2 = ((const float4*)v2s)[c];

    float d2own[4], d2oth[4];   // own-half slot order; softmax is order-invariant
    #pragma unroll
    for (int j = 0; j < 4; ++j) {
        float v = rows[j].x * vv2.x + rows[j].y * vv2.y
                + rows[j].z * vv2.z + rows[j].w * vv2.w;
        #pragma unroll
        for (int off = 1; off <= 16; off <<= 1) v += __shfl_xor(v, off, 64);
        d2own[j] = v;
        d2oth[j] = __shfl_xor(v, 32, 64);
    }

    const float sb = sim_b[0];
    float lown[4], loth[4], m = -INFINITY;
    #pragma unroll
    for (int j = 0; j < 4; ++j) {
        lown[j] = fmaxf(qs + d2own[j] + sb, 0.f);
        loth[j] = fmaxf(qs + d2oth[j] + sb, 0.f);
        m = fmaxf(m, fmaxf(lown[j], loth[j]));
    }
    float pown[4], psum = 0.f;
    #pragma unroll
    for (int j = 0; j < 4; ++j) {
        pown[j] = __expf(lown[j] - m);
        psum += pown[j] + __expf(loth[j] - m);
    }
    const float inv = __builtin_amdgcn_rcpf(psum);

    // weighted slot mix: own-half slots only, then combine halves
    float4 wm = {0.f, 0.f, 0.f, 0.f};
    #pragma unroll
    for (int j = 0; j < 4; ++j) {
        float ps = pown[j] * inv;
        wm.x += ps * rows[j].x;
        wm.y += ps * rows[j].y;
        wm.z += ps * rows[j].z;
        wm.w += ps * rows[j].w;
    }
    wm.x += __shfl_xor(wm.x, 32, 64);
    wm.y += __shfl_xor(wm.y, 32, 64);
    wm.z += __shfl_xor(wm.z, 32, 64);
    wm.w += __shfl_xor(wm.w, 32, 64);
    if (hi == 0) ((float4*)wm_lds[wv])[c] = wm;
    __syncthreads();

    // ---- epilogue: out[b] = wm[b] @ attn_W, split-K across lane halves ----
    // wm read as float4 (ds_read_b128 broadcast), W rows streamed coalesced.
    const float4* W4  = (const float4*)attn_W;
    const float4* wm4 = (const float4*)wm_lds[wv];
    float4 acc = {0.f, 0.f, 0.f, 0.f};
    #pragma unroll
    for (int j4 = 0; j4 < 16; ++j4) {
        const float4 xm = wm4[hi * 16 + j4];
        const int ib = (hi * 64 + j4 * 4) * (H / 4) + c;
        const float4 w0 = W4[ib];
        const float4 w1 = W4[ib + (H / 4)];
        const float4 w2 = W4[ib + 2 * (H / 4)];
        const float4 w3 = W4[ib + 3 * (H / 4)];
        acc.x += xm.x * w0.x + xm.y * w1.x + xm.z * w2.x + xm.w * w3.x;
        acc.y += xm.x * w0.y + xm.y * w1.y + xm.z * w2.y + xm.w * w3.y;
        acc.z += xm.x * w0.z + xm.y * w1.z + xm.z * w2.z + xm.w * w3.z;
        acc.w += xm.x * w0.w + xm.y * w1.w + xm.z * w2.w + xm.w * w3.w;
    }
    acc.x += __shfl_xor(acc.x, 32, 64);
    acc.y += __shfl_xor(acc.y, 32, 64);
    acc.z += __shfl_xor(acc.z, 32, 64);
    acc.w += __shfl_xor(acc.w, 32, 64);
    if (hi == 0) ((float4*)out)[(size_t)b * (H / 4) + c] = acc;
}

extern "C" void kernel_launch(void* const* d_in, const int* in_sizes, int n_in,
                              void* d_out, int out_size, void* d_ws, size_t ws_size,
                              hipStream_t stream) {
    const float* memory   = (const float*)d_in[0];
    const float* o_emb_w  = (const float*)d_in[1];
    const float* o_emb_r  = (const float*)d_in[2];
    const float* attn_W   = (const float*)d_in[3];
    const float* sim_w    = (const float*)d_in[4];
    const float* sim_b    = (const float*)d_in[5];
    const float* forget_w = (const float*)d_in[6];
    const int*   o_rg     = (const int*)d_in[7];
    const int*   d_rg     = (const int*)d_in[8];
    float* out = (float*)d_out;

    const int B = in_sizes[8];  // 4096

    fused_kernel<<<B / BB, 512, 0, stream>>>(
        memory, o_emb_w, o_emb_r, attn_W, sim_w, sim_b, forget_w, o_rg, d_rg, out);
}